// Round 3
// baseline (625.351 us; speedup 1.0000x reference)
//
#include <hip/hip_runtime.h>

// CRF forward scan. B=512 batches, S=1024 steps, T=64 tags.
// new_alpha[b,i] = feat[b,s,i] + logsumexp_j(alpha[b,j] + trans[i,j])
//
// E[i,j] = exp(trans[i,j] - rowmax_i) precomputed once; per step a fp32
// matvec + exp/log. M = alpha[lane 1] range-proxy. Tag 0 underflows to p=0.
//
// R3: wall time = S * (per-step serial chain). R2's chain was dominated by
// the LDS all-to-all (ds_write visibility + 16x ds_read_b128 issue+latency,
// ~900 stall cyc/step; VALUBusy was only 20%). Replace the exchange with
// 64x v_readlane_b32 -> SGPR, consumed directly by v_fmac (VALU allows one
// SGPR operand). Chain becomes pure VALU issue: ~128 insts * ~2-3 cyc.
// No LDS, no barriers, no lgkmcnt in the loop.

constexpr int T = 64;

__global__ __launch_bounds__(64)
void crf_fwd_kernel(const float* __restrict__ feats,
                    const float* __restrict__ masks,
                    const float* __restrict__ trans,
                    float* __restrict__ out,
                    int S)
{
    const int b    = blockIdx.x;
    const int lane = threadIdx.x;   // tag index i

    // ---- one-time: load transitions row i=lane, rowmax, exponentiate ----
    float E[T];
    const float* tr = trans + lane * T;
    float rowmax = -3.4e38f;
#pragma unroll
    for (int j = 0; j < T; ++j) {
        E[j] = tr[j];
        rowmax = fmaxf(rowmax, E[j]);
    }
#pragma unroll
    for (int j = 0; j < T; ++j) {
        E[j] = __expf(E[j] - rowmax);   // in [0,1]
    }

    const float* fb = feats + (size_t)b * S * T;
    const float* mb = masks + (size_t)b * S;

    float alpha = fb[lane];            // alpha0 = feats[:,0]

    // 2-deep software pipeline for next-step feat/mask
    float feat0 = fb[T + lane];        // step 1
    float m0    = mb[1];
    float feat1 = fb[2 * T + lane];    // step 2
    float m1    = mb[2];

    for (int s = 1; s < S; ++s) {
        const int sp = (s + 2 < S) ? (s + 2) : (S - 1);
        const float feat_n = fb[sp * T + lane];
        const float m_n    = mb[sp];

        // range proxy M = alpha[lane 1] (first non-degenerate tag)
        const float M = __int_as_float(
            __builtin_amdgcn_readlane(__float_as_int(alpha), 1));
        const float p = __expf(alpha - M);
        const int pi = __float_as_int(p);

        // matvec row i=lane: acc = sum_j E[j] * p[j].
        // p[j] broadcast via v_readlane -> SGPR (no LDS in the chain);
        // 64 independent readlanes pipeline at VALU issue rate; 8 acc chains.
        float acc[8] = {0.f, 0.f, 0.f, 0.f, 0.f, 0.f, 0.f, 0.f};
#pragma unroll
        for (int j = 0; j < T; ++j) {
            const float pj = __int_as_float(__builtin_amdgcn_readlane(pi, j));
            acc[j & 7] = fmaf(E[j], pj, acc[j & 7]);
        }
        const float total = ((acc[0] + acc[4]) + (acc[1] + acc[5]))
                          + ((acc[2] + acc[6]) + (acc[3] + acc[7]));

        const float na = feat0 + rowmax + M + __logf(total);
        alpha = m0 * na + (1.0f - m0) * alpha;  // exact passthrough for m in {0,1}

        feat0 = feat1; m0 = m1;
        feat1 = feat_n; m1 = m_n;
    }

    out[b * T + lane] = alpha;
}

extern "C" void kernel_launch(void* const* d_in, const int* in_sizes, int n_in,
                              void* d_out, int out_size, void* d_ws, size_t ws_size,
                              hipStream_t stream) {
    const float* feats = (const float*)d_in[0];   // (B, S, T) fp32
    const float* masks = (const float*)d_in[1];   // (B, S)    fp32
    const float* trans = (const float*)d_in[2];   // (T, T)    fp32
    float* out = (float*)d_out;                   // (B, T)    fp32

    const int S = 1024;                 // problem shape (B=512, S=1024, T=64)
    const int B = in_sizes[1] / S;

    crf_fwd_kernel<<<B, T, 0, stream>>>(feats, masks, trans, out, S);
}

// Round 4
// 503.747 us; speedup vs baseline: 1.2414x; 1.2414x over previous
//
#include <hip/hip_runtime.h>

// CRF forward scan. B=512 batches, S=1024 steps, T=64 tags.
// new_alpha[b,i] = feat[b,s,i] + logsumexp_j(alpha[b,j] + trans[i,j])
//
// E[i,j] = exp(trans[i,j] - rowmax_i) precomputed once; per step a fp32
// matvec + exp/log. M = alpha[lane 1] range-proxy. Tag 0 underflows to p=0.
// p[j] broadcast via v_readlane -> SGPR consumed directly by v_fmac (R3).
//
// R4: R2/R3 both stalled ~900 cyc/step == HBM load latency: the 2-deep
// feat rotation was collapsed by the compiler (feat0 at step s == fb[s*T+lane],
// trivially forward-substitutable), so the load was issued in the consuming
// iteration. Fix: depth-8 ring buffer, chunk-unrolled; each step consumes
// slot k and re-issues the load for step s+8 into that slot -> load-to-use
// distance of 8 steps (~2000+ cyc), precise vmcnt overlap.

constexpr int T = 64;
constexpr int D = 8;   // prefetch depth (steps)

__global__ __launch_bounds__(64)
void crf_fwd_kernel(const float* __restrict__ feats,
                    const float* __restrict__ masks,
                    const float* __restrict__ trans,
                    float* __restrict__ out,
                    int S)
{
    const int b    = blockIdx.x;
    const int lane = threadIdx.x;   // tag index i

    // ---- one-time: load transitions row i=lane, rowmax, exponentiate ----
    float E[T];
    const float* tr = trans + lane * T;
    float rowmax = -3.4e38f;
#pragma unroll
    for (int j = 0; j < T; ++j) {
        E[j] = tr[j];
        rowmax = fmaxf(rowmax, E[j]);
    }
#pragma unroll
    for (int j = 0; j < T; ++j) {
        E[j] = __expf(E[j] - rowmax);   // in [0,1]
    }

    const float* fb = feats + (size_t)b * S * T;
    const float* mb = masks + (size_t)b * S;

    float alpha = fb[lane];            // alpha0 = feats[:,0]

    // ring buffer: slot k holds feat/mask for the k-th upcoming step
    float f[D], mk[D];
#pragma unroll
    for (int k = 0; k < D; ++k) {
        f[k]  = fb[(1 + k) * T + lane];
        mk[k] = mb[1 + k];
    }

    // one scan step; consumes (feat, m), updates alpha
#define CRF_STEP(feat_, m_)                                                   \
    {                                                                         \
        const float M = __int_as_float(                                       \
            __builtin_amdgcn_readlane(__float_as_int(alpha), 1));             \
        const float p = __expf(alpha - M);                                    \
        const int  pi = __float_as_int(p);                                    \
        float acc[8] = {0.f, 0.f, 0.f, 0.f, 0.f, 0.f, 0.f, 0.f};              \
        _Pragma("unroll")                                                     \
        for (int j = 0; j < T; ++j) {                                         \
            const float pj =                                                  \
                __int_as_float(__builtin_amdgcn_readlane(pi, j));             \
            acc[j & 7] = fmaf(E[j], pj, acc[j & 7]);                          \
        }                                                                     \
        const float total = ((acc[0] + acc[4]) + (acc[1] + acc[5]))           \
                          + ((acc[2] + acc[6]) + (acc[3] + acc[7]));          \
        const float na = (feat_) + rowmax + M + __logf(total);                \
        alpha = (m_) * na + (1.0f - (m_)) * alpha;                            \
    }

    // main chunked loop: steps sc..sc+D-1, prefetching steps sc+D..sc+2D-1
    int sc = 1;
    for (; sc + D <= S; sc += D) {
#pragma unroll
        for (int k = 0; k < D; ++k) {
            const int s    = sc + k;
            const int spre = (s + D < S) ? (s + D) : (S - 1);
            // issue next-chunk load for this slot FIRST (independent of alpha)
            const float fpre = fb[spre * T + lane];
            const float mpre = mb[spre];
            const float feat = f[k];
            const float m    = mk[k];
            CRF_STEP(feat, m);
            f[k]  = fpre;
            mk[k] = mpre;
        }
    }
    // tail: remaining steps sc..S-1 are already in ring slots 0..
#pragma unroll
    for (int k = 0; k < D - 1; ++k) {
        if (sc + k < S) {
            const float feat = f[k];
            const float m    = mk[k];
            CRF_STEP(feat, m);
        }
    }
#undef CRF_STEP

    out[b * T + lane] = alpha;
}

extern "C" void kernel_launch(void* const* d_in, const int* in_sizes, int n_in,
                              void* d_out, int out_size, void* d_ws, size_t ws_size,
                              hipStream_t stream) {
    const float* feats = (const float*)d_in[0];   // (B, S, T) fp32
    const float* masks = (const float*)d_in[1];   // (B, S)    fp32
    const float* trans = (const float*)d_in[2];   // (T, T)    fp32
    float* out = (float*)d_out;                   // (B, T)    fp32

    const int S = 1024;                 // problem shape (B=512, S=1024, T=64)
    const int B = in_sizes[1] / S;

    crf_fwd_kernel<<<B, T, 0, stream>>>(feats, masks, trans, out, S);
}